// Round 1
// baseline (490.149 us; speedup 1.0000x reference)
//
#include <hip/hip_runtime.h>

// PosteriorRotationN: B=8,T=120,N=24,D=48,C=1128,DE=256
// y[b,t,n,:] = x[b,t,n,:] + dx, dx[e] = sum_{d>e} x[d]*g(sp(d,e)) - sum_{d<e} x[d]*g(sp(e,d))
// sp[t,c] = x[t,:]·kv[c,:],  kv[c,d] = ctx[b,c,n,:]·Wkv[d,:] + bkv[d],  g = 0.1*tanh(s)

constexpr int Bc = 8, Tc = 120, Nc = 24, Dc = 48, Cc = 1128, DEc = 256;
constexpr int BNc = Bc * Nc;          // 192
constexpr float EPS_ = 0.1f;

// ---------------- K0: out = x (identity term, same layout) ----------------
__global__ void k0_copy(const float* __restrict__ x, float* __restrict__ out, int n4) {
    int i = blockIdx.x * blockDim.x + threadIdx.x;
    if (i < n4) reinterpret_cast<float4*>(out)[i] = reinterpret_cast<const float4*>(x)[i];
}

// ---------------- K1: kv[bn][c][d] (f32 GEMM, K=256) ----------------
constexpr int CB = 64, KB = 32;
__global__ __launch_bounds__(256) void k1_kv(const float* __restrict__ ctx,
                                             const float* __restrict__ Wkv,
                                             const float* __restrict__ bkv,
                                             float* __restrict__ kv) {
    __shared__ float sA[CB][KB + 4];   // ctx tile [c][e]
    __shared__ float sB[Dc][KB + 4];   // Wkv tile [d][e]
    const int bn = blockIdx.x;
    const int c0 = blockIdx.y * CB;
    const int b = bn / Nc, n = bn % Nc;
    const int tid = threadIdx.x;
    const int cg = tid >> 4, dg = tid & 15;      // 16 x 16 thread grid; tile 4c x 3d
    const float* ctx_bn = ctx + ((size_t)b * Cc * Nc + n) * DEc;
    float acc[4][3] = {{0.f, 0.f, 0.f}};

    for (int e0 = 0; e0 < DEc; e0 += KB) {
        for (int l = tid; l < CB * (KB / 4); l += 256) {
            int cr = l >> 3, ev = (l & 7) << 2;
            int c = c0 + cr;
            float4 v = make_float4(0.f, 0.f, 0.f, 0.f);
            if (c < Cc) v = *reinterpret_cast<const float4*>(ctx_bn + (size_t)c * (Nc * DEc) + e0 + ev);
            *reinterpret_cast<float4*>(&sA[cr][ev]) = v;
        }
        for (int l = tid; l < Dc * (KB / 4); l += 256) {
            int dr = l >> 3, ev = (l & 7) << 2;
            *reinterpret_cast<float4*>(&sB[dr][ev]) = *reinterpret_cast<const float4*>(Wkv + dr * DEc + e0 + ev);
        }
        __syncthreads();
        #pragma unroll
        for (int e = 0; e < KB; e += 4) {
            float4 a[4], bb[3];
            #pragma unroll
            for (int ci = 0; ci < 4; ++ci) a[ci] = *reinterpret_cast<const float4*>(&sA[cg * 4 + ci][e]);
            #pragma unroll
            for (int di = 0; di < 3; ++di) bb[di] = *reinterpret_cast<const float4*>(&sB[dg * 3 + di][e]);
            #pragma unroll
            for (int ci = 0; ci < 4; ++ci)
                #pragma unroll
                for (int di = 0; di < 3; ++di)
                    acc[ci][di] += a[ci].x * bb[di].x + a[ci].y * bb[di].y
                                 + a[ci].z * bb[di].z + a[ci].w * bb[di].w;
        }
        __syncthreads();
    }
    #pragma unroll
    for (int ci = 0; ci < 4; ++ci) {
        int c = c0 + cg * 4 + ci;
        if (c >= Cc) continue;
        float* dst = kv + ((size_t)bn * Cc + c) * Dc + dg * 3;
        #pragma unroll
        for (int di = 0; di < 3; ++di) dst[di] = acc[ci][di] + bkv[dg * 3 + di];
    }
}

// ---------------- K2: fused sp + tanh + skew-matvec, atomic into out ----------------
constexpr int S_ = 8, CSL = Cc / S_ /*141*/, KC = 47;
__global__ __launch_bounds__(256) void k2_fused(const float* __restrict__ x,
                                                const float* __restrict__ kv,
                                                float* __restrict__ out) {
    __shared__ float sX[Tc][Dc + 1];           // X rows, runtime-indexed by (i,j)
    __shared__ float sDX[Tc][Dc + 1];          // dx accumulator (LDS atomics)
    __shared__ float sKV[KC][Dc];              // kv chunk, broadcast reads
    __shared__ unsigned short sPair[CSL];      // (i<<8)|j per slice-local c
    const int bn = blockIdx.x, slice = blockIdx.y;
    const int b = bn / Nc, n = bn % Nc;
    const int tid = threadIdx.x;
    const int q = tid >> 6, tl = tid & 63;     // wave q handles cc % 4 == q

    for (int l = tid; l < Tc * (Dc / 4); l += 256) {
        int t = l / 12, dv = (l % 12) * 4;
        float4 v = *reinterpret_cast<const float4*>(x + (((size_t)b * Tc + t) * Nc + n) * Dc + dv);
        sX[t][dv + 0] = v.x; sX[t][dv + 1] = v.y; sX[t][dv + 2] = v.z; sX[t][dv + 3] = v.w;
        sDX[t][dv + 0] = 0.f; sDX[t][dv + 1] = 0.f; sDX[t][dv + 2] = 0.f; sDX[t][dv + 3] = 0.f;
    }
    for (int l = tid; l < CSL; l += 256) {
        int c = slice * CSL + l;
        int i = (int)((1.0f + sqrtf(1.0f + 8.0f * (float)c)) * 0.5f);
        while (i * (i - 1) / 2 > c) --i;
        while ((i + 1) * i / 2 <= c) ++i;
        int j = c - i * (i - 1) / 2;
        sPair[l] = (unsigned short)((i << 8) | j);
    }

    const bool act = (tl < 60);
    const int t1 = tl, t2 = tl + 60;           // each thread owns 2 t-rows
    float X1[Dc], X2[Dc];
    __syncthreads();
    if (act) {
        #pragma unroll
        for (int k = 0; k < Dc; ++k) { X1[k] = sX[t1][k]; X2[k] = sX[t2][k]; }
    }

    for (int ch = 0; ch < CSL / KC; ++ch) {
        __syncthreads();
        for (int l = tid; l < KC * 12; l += 256) {
            int cr = l / 12, dv = (l % 12) * 4;
            *reinterpret_cast<float4*>(&sKV[cr][dv]) =
                *reinterpret_cast<const float4*>(kv + ((size_t)bn * Cc + slice * CSL + ch * KC + cr) * Dc + dv);
        }
        __syncthreads();
        if (act) {
            for (int cc = q; cc < KC; cc += 4) {
                unsigned int pij = sPair[ch * KC + cc];
                int i = (int)(pij >> 8), j = (int)(pij & 255u);
                float s10 = 0, s11 = 0, s12 = 0, s13 = 0;
                float s20 = 0, s21 = 0, s22 = 0, s23 = 0;
                #pragma unroll
                for (int qq = 0; qq < 12; ++qq) {
                    float4 kq = *reinterpret_cast<const float4*>(&sKV[cc][qq * 4]);
                    s10 += X1[qq * 4 + 0] * kq.x; s11 += X1[qq * 4 + 1] * kq.y;
                    s12 += X1[qq * 4 + 2] * kq.z; s13 += X1[qq * 4 + 3] * kq.w;
                    s20 += X2[qq * 4 + 0] * kq.x; s21 += X2[qq * 4 + 1] * kq.y;
                    s22 += X2[qq * 4 + 2] * kq.z; s23 += X2[qq * 4 + 3] * kq.w;
                }
                float sp1 = (s10 + s11) + (s12 + s13);
                float sp2 = (s20 + s21) + (s22 + s23);
                // g = 0.1*tanh(s) = 0.1 - 0.2/(exp(2s)+1), branch-free, inf-safe
                float g1 = EPS_ - 0.2f * __builtin_amdgcn_rcpf(__expf(2.f * sp1) + 1.f);
                float g2 = EPS_ - 0.2f * __builtin_amdgcn_rcpf(__expf(2.f * sp2) + 1.f);
                float xi1 = sX[t1][i], xj1 = sX[t1][j];
                float xi2 = sX[t2][i], xj2 = sX[t2][j];
                atomicAdd(&sDX[t1][j],  xi1 * g1);
                atomicAdd(&sDX[t1][i], -xj1 * g1);
                atomicAdd(&sDX[t2][j],  xi2 * g2);
                atomicAdd(&sDX[t2][i], -xj2 * g2);
            }
        }
    }
    __syncthreads();
    for (int l = tid; l < Tc * Dc; l += 256) {
        int t = l / Dc, d = l % Dc;
        atomicAdd(out + (((size_t)b * Tc + t) * Nc + n) * Dc + d, sDX[t][d]);
    }
}

extern "C" void kernel_launch(void* const* d_in, const int* in_sizes, int n_in,
                              void* d_out, int out_size, void* d_ws, size_t ws_size,
                              hipStream_t stream) {
    (void)in_sizes; (void)n_in; (void)out_size; (void)ws_size;
    const float* x   = (const float*)d_in[0];
    const float* ctx = (const float*)d_in[1];
    const float* Wkv = (const float*)d_in[2];
    const float* bkv = (const float*)d_in[3];
    float* out  = (float*)d_out;
    float* kvws = (float*)d_ws;   // needs 192*1128*48*4 = 41.6 MB scratch

    const int n4 = Bc * Tc * Nc * Dc / 4;
    k0_copy<<<dim3((n4 + 255) / 256), dim3(256), 0, stream>>>(x, out, n4);
    k1_kv<<<dim3(BNc, (Cc + CB - 1) / CB), dim3(256), 0, stream>>>(ctx, Wkv, bkv, kvws);
    k2_fused<<<dim3(BNc, S_), dim3(256), 0, stream>>>(x, kvws, out);
}

// Round 2
// 122.586 us; speedup vs baseline: 3.9984x; 3.9984x over previous
//
#include <hip/hip_runtime.h>

// PosteriorRotationN: B=8,T=120,N=24,D=48,C=1128,DE=256
// kv[bn][c][d] = ctx[b,c,n,:]·Wkv[d,:] + bkv[d]          (K1, bf16 MFMA, HBM-bound)
// sp[t][c] = x[t,:]·kv[c,:]; g=0.1*tanh(sp)              (K2 phase A, bf16 MFMA)
// dx[t][e] = sum_{d>e} x[d]g(c(d,e)) - sum_{d<e} x[d]g(c(e,d)); out = x + dx  (K2 phase B, gather)

constexpr int Bc = 8, Tc = 120, Nc = 24, Dc = 48, Cc = 1128, DEc = 256;
constexpr int BNc = Bc * Nc;        // 192
constexpr int KVP = 64;             // kv row padded to 64 (zeros at 48..63)

using short8 = __attribute__((ext_vector_type(8))) short;
using f32x4  = __attribute__((ext_vector_type(4))) float;

__device__ __forceinline__ ushort f2b(float f) {
    union { float f; unsigned u; } v; v.f = f;
    unsigned r = (v.u + 0x7fffu + ((v.u >> 16) & 1u)) >> 16;
    return (ushort)r;
}

// ---------------- K1: kv GEMM, bf16 MFMA ----------------
// grid (192 bn, 9 c-blocks), 256 thr. BM=128(c), N=48(d), K=256 in 4 steps of 64.
constexpr int SWs = 264;  // Wkv LDS stride (bf16 elems): 528B row, 16B-aligned, 2-way bank
constexpr int SAs = 72;   // ctx tile LDS stride: 144B row
__global__ __launch_bounds__(256) void k1_kv(const float* __restrict__ ctx,
                                             const float* __restrict__ Wkv,
                                             const float* __restrict__ bkv,
                                             ushort* __restrict__ kvb) {
    __shared__ ushort sW[Dc * SWs];     // 25344 B, full K=256
    __shared__ ushort sA[128 * SAs];    // 18432 B, one K-step
    const int bn = blockIdx.x, c0 = blockIdx.y * 128;
    const int b = bn / Nc, n = bn % Nc;
    const int tid = threadIdx.x, wave = tid >> 6, lane = tid & 63;
    const int tr = lane & 15, kg = lane >> 4;
    const float* ctxb = ctx + (size_t)b * Cc * Nc * DEc + (size_t)n * DEc;

    // stage Wkv (f32 -> bf16), once
    for (int l = tid; l < Dc * 64; l += 256) {
        int d = l >> 6, e4 = (l & 63) << 2;
        float4 w = *reinterpret_cast<const float4*>(Wkv + d * DEc + e4);
        ushort4 u = make_ushort4(f2b(w.x), f2b(w.y), f2b(w.z), f2b(w.w));
        *reinterpret_cast<ushort4*>(&sW[d * SWs + e4]) = u;
    }
    f32x4 acc[2][3];
    #pragma unroll
    for (int mf = 0; mf < 2; ++mf)
        #pragma unroll
        for (int nf = 0; nf < 3; ++nf) acc[mf][nf] = (f32x4){0.f, 0.f, 0.f, 0.f};

    for (int e0 = 0; e0 < DEc; e0 += 64) {
        __syncthreads();
        #pragma unroll
        for (int pass = 0; pass < 8; ++pass) {          // 16 rows x 16 lanes(16B) per pass
            int r = pass * 16 + (tid >> 4), e = (tid & 15) << 2;
            int c = c0 + r;
            float4 v = make_float4(0.f, 0.f, 0.f, 0.f);
            if (c < Cc) v = *reinterpret_cast<const float4*>(ctxb + (size_t)c * (Nc * DEc) + e0 + e);
            ushort4 u = make_ushort4(f2b(v.x), f2b(v.y), f2b(v.z), f2b(v.w));
            *reinterpret_cast<ushort4*>(&sA[r * SAs + e]) = u;
        }
        __syncthreads();
        short8 af[2][2], bfg[3][2];
        #pragma unroll
        for (int mf = 0; mf < 2; ++mf)
            #pragma unroll
            for (int kf = 0; kf < 2; ++kf)
                af[mf][kf] = *reinterpret_cast<const short8*>(&sA[(wave * 32 + mf * 16 + tr) * SAs + kf * 32 + kg * 8]);
        #pragma unroll
        for (int nf = 0; nf < 3; ++nf)
            #pragma unroll
            for (int kf = 0; kf < 2; ++kf)
                bfg[nf][kf] = *reinterpret_cast<const short8*>(&sW[(nf * 16 + tr) * SWs + e0 + kf * 32 + kg * 8]);
        #pragma unroll
        for (int mf = 0; mf < 2; ++mf)
            #pragma unroll
            for (int nf = 0; nf < 3; ++nf)
                #pragma unroll
                for (int kf = 0; kf < 2; ++kf)
                    acc[mf][nf] = __builtin_amdgcn_mfma_f32_16x16x32_bf16(af[mf][kf], bfg[nf][kf], acc[mf][nf], 0, 0, 0);
    }
    // epilogue: +bias, store bf16 to kvb[bn][c][64]
    #pragma unroll
    for (int nf = 0; nf < 3; ++nf) {
        int d = nf * 16 + tr;
        float bias = bkv[d];
        #pragma unroll
        for (int mf = 0; mf < 2; ++mf) {
            int cbase = c0 + wave * 32 + mf * 16 + kg * 4;
            #pragma unroll
            for (int r = 0; r < 4; ++r) {
                int c = cbase + r;
                if (c < Cc) kvb[((size_t)bn * Cc + c) * KVP + d] = f2b(acc[mf][nf][r] + bias);
            }
        }
    }
    // zero the K-pad d=48..63 (16 bf16 = 32B per row; 2 threads/row)
    {
        int r = tid >> 1, c = c0 + r;
        if (c < Cc) {
            uint4 z = make_uint4(0u, 0u, 0u, 0u);
            *reinterpret_cast<uint4*>(&kvb[((size_t)bn * Cc + c) * KVP + 48 + (tid & 1) * 8]) = z;
        }
    }
}

// ---------------- K2: sp MFMA + tanh + gather matvec ----------------
// grid 1536 = 192 bn x 8 t-tiles(16), XCD-swizzled so a bn's tiles share an XCD L2.
constexpr int SGs = 1136;  // sG f32 stride
__global__ __launch_bounds__(256) void k2_fused(const float* __restrict__ x,
                                                const ushort* __restrict__ kvb,
                                                float* __restrict__ out) {
    __shared__ float  sG[16 * SGs];    // 72704 B
    __shared__ float  sXf[16 * 52];    // 3328 B
    __shared__ ushort sXb[16 * 72];    // 2304 B (K-padded to 64 w/ zeros)
    const int L = blockIdx.x;
    const int bn = (L & 7) + 8 * (L >> 6);   // bn%8 == XCD slot
    const int tt = (L >> 3) & 7;
    const int b = bn / Nc, n = bn % Nc, t0 = tt * 16;
    const int tid = threadIdx.x, wave = tid >> 6, lane = tid & 63;
    const int tr = lane & 15, kg = lane >> 4;

    for (int l = tid; l < 16 * 72 / 4; l += 256)
        *reinterpret_cast<ushort4*>(&sXb[l * 4]) = make_ushort4(0, 0, 0, 0);
    __syncthreads();
    if (tid < 192) {
        int t = tid / 12, dv = (tid % 12) * 4, tg = t0 + t;
        float4 v = make_float4(0.f, 0.f, 0.f, 0.f);
        if (tg < Tc) v = *reinterpret_cast<const float4*>(x + (((size_t)b * Tc + tg) * Nc + n) * Dc + dv);
        *reinterpret_cast<float4*>(&sXf[t * 52 + dv]) = v;
        *reinterpret_cast<ushort4*>(&sXb[t * 72 + dv]) = make_ushort4(f2b(v.x), f2b(v.y), f2b(v.z), f2b(v.w));
    }
    __syncthreads();
    // A-frags (t=lane&15, k contiguous-8) hoisted to regs
    const short8 af0 = *reinterpret_cast<const short8*>(&sXb[tr * 72 + kg * 8]);
    const short8 af1 = *reinterpret_cast<const short8*>(&sXb[tr * 72 + 32 + kg * 8]);
    const ushort* kvbn = kvb + (size_t)bn * Cc * KVP;
    // phase A: 71 c-frags over 4 waves; B-frags straight from global (L2)
    for (int nf = wave; nf < 71; nf += 4) {
        int c = nf * 16 + tr;
        int ce = c < Cc ? c : Cc - 1;
        short8 b0 = *reinterpret_cast<const short8*>(&kvbn[(size_t)ce * KVP + kg * 8]);
        short8 b1 = *reinterpret_cast<const short8*>(&kvbn[(size_t)ce * KVP + 32 + kg * 8]);
        f32x4 a = (f32x4){0.f, 0.f, 0.f, 0.f};
        a = __builtin_amdgcn_mfma_f32_16x16x32_bf16(af0, b0, a, 0, 0, 0);
        a = __builtin_amdgcn_mfma_f32_16x16x32_bf16(af1, b1, a, 0, 0, 0);
        #pragma unroll
        for (int r = 0; r < 4; ++r) {   // C/D: col=lane&15 (=c), row=kg*4+r (=t)
            float g = 0.1f - 0.2f * __builtin_amdgcn_rcpf(__expf(2.0f * a[r]) + 1.0f);
            sG[(kg * 4 + r) * SGs + c] = g;
        }
    }
    __syncthreads();
    // phase B: thread owns 3 (t,e) pairs; 48-iter gather, no atomics
    int ea[3], ta[3], tea[3];
    float dxa[3];
    #pragma unroll
    for (int p = 0; p < 3; ++p) {
        int idx = tid + p * 256;
        ta[p] = idx / 48; ea[p] = idx % 48;
        tea[p] = ea[p] * (ea[p] - 1) / 2;
        dxa[p] = 0.f;
    }
    int td = 0;
    #pragma unroll 4
    for (int d = 0; d < 48; ++d) {
        #pragma unroll
        for (int p = 0; p < 3; ++p) {
            bool gt = d > ea[p];
            int c = gt ? (td + ea[p]) : (tea[p] + d);
            float gv = sG[ta[p] * SGs + c];
            float xv = sXf[ta[p] * 52 + d];
            float m = gt ? xv : -xv;
            if (d == ea[p]) m = 0.f;
            dxa[p] = fmaf(m, gv, dxa[p]);
        }
        td += d;
    }
    #pragma unroll
    for (int p = 0; p < 3; ++p) {
        int tg = t0 + ta[p];
        if (tg < Tc)
            out[(((size_t)b * Tc + tg) * Nc + n) * Dc + ea[p]] = sXf[ta[p] * 52 + ea[p]] + dxa[p];
    }
}

extern "C" void kernel_launch(void* const* d_in, const int* in_sizes, int n_in,
                              void* d_out, int out_size, void* d_ws, size_t ws_size,
                              hipStream_t stream) {
    (void)in_sizes; (void)n_in; (void)out_size; (void)ws_size;
    const float* x   = (const float*)d_in[0];
    const float* ctx = (const float*)d_in[1];
    const float* Wkv = (const float*)d_in[2];
    const float* bkv = (const float*)d_in[3];
    float* out   = (float*)d_out;
    ushort* kvb  = (ushort*)d_ws;   // 192*1128*64*2 = 27.7 MB

    k1_kv<<<dim3(BNc, 9), dim3(256), 0, stream>>>(ctx, Wkv, bkv, kvb);
    k2_fused<<<dim3(BNc * 8), dim3(256), 0, stream>>>(x, kvb, out);
}

// Round 3
// 98.365 us; speedup vs baseline: 4.9830x; 1.2462x over previous
//
#include <hip/hip_runtime.h>

// PosteriorRotationN: B=8,T=120,N=24,D=48,C=1128,DE=256
// kv[bn][c][d] = ctx[b,c,n,:]·Wkv[d,:] + bkv[d]          (K1, bf16 MFMA, barrier-free K-loop)
// sp[t][c] = x[t,:]·kv[c,:]; g=0.1*tanh(sp)              (K2 phase A, bf16 MFMA)
// dx[t][e] = sum_{d>e} x[d]g(c(d,e)) - sum_{d<e} x[d]g(c(e,d)); out = x + dx  (K2 phase B, gather)

constexpr int Bc = 8, Tc = 120, Nc = 24, Dc = 48, Cc = 1128, DEc = 256;
constexpr int BNc = Bc * Nc;        // 192
constexpr int KVP = 64;             // kv row padded to 64 (zeros at 48..63)

using short8 = __attribute__((ext_vector_type(8))) short;
using f32x4  = __attribute__((ext_vector_type(4))) float;

__device__ __forceinline__ ushort f2b(float f) {
    union { float f; unsigned u; } v; v.f = f;
    unsigned r = (v.u + 0x7fffu + ((v.u >> 16) & 1u)) >> 16;
    return (ushort)r;
}
__device__ __forceinline__ short8 pack8(const float4& a, const float4& b) {
    short8 r;
    r[0] = (short)f2b(a.x); r[1] = (short)f2b(a.y); r[2] = (short)f2b(a.z); r[3] = (short)f2b(a.w);
    r[4] = (short)f2b(b.x); r[5] = (short)f2b(b.y); r[6] = (short)f2b(b.z); r[7] = (short)f2b(b.w);
    return r;
}

// ---------------- K1: kv GEMM, bf16 MFMA, A direct-from-global ----------------
// grid (192 bn, 9 c-blocks), 256 thr = 4 independent waves, each owns 32 c-rows.
constexpr int SWs = 264;  // Wkv LDS stride (bf16 elems)
constexpr int STs = 72;   // transpose-staging stride (bf16 elems), 144 B, 16B-aligned
__global__ __launch_bounds__(256) void k1_kv(const float* __restrict__ ctx,
                                             const float* __restrict__ Wkv,
                                             const float* __restrict__ bkv,
                                             ushort* __restrict__ kvb) {
    __shared__ ushort sW[Dc * SWs];          // 25344 B, full K=256 of Wkv (bf16)
    __shared__ ushort sT[4][32 * STs];       // 18432 B, per-wave output transpose tile
    const int bn = blockIdx.x, c0 = blockIdx.y * 128;
    const int b = bn / Nc, n = bn % Nc;
    const int tid = threadIdx.x, wave = tid >> 6, lane = tid & 63;
    const int tr = lane & 15, kg = lane >> 4;
    const float* ctxb = ctx + ((size_t)b * Cc * Nc + n) * DEc;

    // stage Wkv (f32 -> bf16) once; only barrier before the K-loop
    for (int l = tid; l < Dc * 64; l += 256) {
        int d = l >> 6, e4 = (l & 63) << 2;
        float4 w = *reinterpret_cast<const float4*>(Wkv + d * DEc + e4);
        ushort4 u = make_ushort4(f2b(w.x), f2b(w.y), f2b(w.z), f2b(w.w));
        *reinterpret_cast<ushort4*>(&sW[d * SWs + e4]) = u;
    }
    __syncthreads();

    // per-lane A rows (clamped; results for c>=Cc discarded at store)
    const float* arow[2];
    #pragma unroll
    for (int mf = 0; mf < 2; ++mf) {
        int c = c0 + wave * 32 + mf * 16 + tr;
        arow[mf] = ctxb + (size_t)(c < Cc ? c : Cc - 1) * (Nc * DEc);
    }

    f32x4 acc[2][3];
    #pragma unroll
    for (int mf = 0; mf < 2; ++mf)
        #pragma unroll
        for (int nf = 0; nf < 3; ++nf) acc[mf][nf] = (f32x4){0.f, 0.f, 0.f, 0.f};

    #pragma unroll
    for (int ks = 0; ks < 8; ++ks) {           // K=256 in 8 steps of 32, no barriers
        const int e0 = ks * 32 + kg * 8;
        short8 af[2];
        #pragma unroll
        for (int mf = 0; mf < 2; ++mf) {
            float4 a0 = *reinterpret_cast<const float4*>(arow[mf] + e0);
            float4 a1 = *reinterpret_cast<const float4*>(arow[mf] + e0 + 4);
            af[mf] = pack8(a0, a1);
        }
        short8 bf[3];
        #pragma unroll
        for (int nf = 0; nf < 3; ++nf)
            bf[nf] = *reinterpret_cast<const short8*>(&sW[(nf * 16 + tr) * SWs + ks * 32 + kg * 8]);
        #pragma unroll
        for (int mf = 0; mf < 2; ++mf)
            #pragma unroll
            for (int nf = 0; nf < 3; ++nf)
                acc[mf][nf] = __builtin_amdgcn_mfma_f32_16x16x32_bf16(af[mf], bf[nf], acc[mf][nf], 0, 0, 0);
    }

    // epilogue: +bias, transpose through per-wave LDS tile, coalesced stores
    float bias[3];
    #pragma unroll
    for (int nf = 0; nf < 3; ++nf) bias[nf] = bkv[nf * 16 + tr];
    #pragma unroll
    for (int mf = 0; mf < 2; ++mf)
        #pragma unroll
        for (int nf = 0; nf < 3; ++nf)
            #pragma unroll
            for (int r = 0; r < 4; ++r)
                sT[wave][(mf * 16 + kg * 4 + r) * STs + nf * 16 + tr] = f2b(acc[mf][nf][r] + bias[nf]);
    {   // zero pad cols 48..63 (16 bf16 = two 16B chunks per row; 2 lanes/row)
        int row = lane >> 1, half = lane & 1;
        short8 z = (short8){0, 0, 0, 0, 0, 0, 0, 0};
        *reinterpret_cast<short8*>(&sT[wave][row * STs + 48 + half * 8]) = z;
    }
    __syncthreads();
    #pragma unroll
    for (int p = 0; p < 4; ++p) {
        int row = p * 8 + (lane >> 3), colv = (lane & 7) * 8;
        short8 v = *reinterpret_cast<const short8*>(&sT[wave][row * STs + colv]);
        int c = c0 + wave * 32 + row;
        if (c < Cc)
            *reinterpret_cast<short8*>(&kvb[((size_t)bn * Cc + c) * KVP + colv]) = v;
    }
}

// ---------------- K2: sp MFMA + tanh + gather matvec (unchanged) ----------------
// grid 1536 = 192 bn x 8 t-tiles(16), XCD-swizzled so a bn's tiles share an XCD L2.
constexpr int SGs = 1136;  // sG f32 stride
__global__ __launch_bounds__(256) void k2_fused(const float* __restrict__ x,
                                                const ushort* __restrict__ kvb,
                                                float* __restrict__ out) {
    __shared__ float  sG[16 * SGs];    // 72704 B
    __shared__ float  sXf[16 * 52];    // 3328 B
    __shared__ ushort sXb[16 * 72];    // 2304 B (K-padded to 64 w/ zeros)
    const int L = blockIdx.x;
    const int bn = (L & 7) + 8 * (L >> 6);   // bn%8 == XCD slot
    const int tt = (L >> 3) & 7;
    const int b = bn / Nc, n = bn % Nc, t0 = tt * 16;
    const int tid = threadIdx.x, wave = tid >> 6, lane = tid & 63;
    const int tr = lane & 15, kg = lane >> 4;

    for (int l = tid; l < 16 * 72 / 4; l += 256)
        *reinterpret_cast<ushort4*>(&sXb[l * 4]) = make_ushort4(0, 0, 0, 0);
    __syncthreads();
    if (tid < 192) {
        int t = tid / 12, dv = (tid % 12) * 4, tg = t0 + t;
        float4 v = make_float4(0.f, 0.f, 0.f, 0.f);
        if (tg < Tc) v = *reinterpret_cast<const float4*>(x + (((size_t)b * Tc + tg) * Nc + n) * Dc + dv);
        *reinterpret_cast<float4*>(&sXf[t * 52 + dv]) = v;
        *reinterpret_cast<ushort4*>(&sXb[t * 72 + dv]) = make_ushort4(f2b(v.x), f2b(v.y), f2b(v.z), f2b(v.w));
    }
    __syncthreads();
    // A-frags (t=lane&15, k contiguous-8) hoisted to regs
    const short8 af0 = *reinterpret_cast<const short8*>(&sXb[tr * 72 + kg * 8]);
    const short8 af1 = *reinterpret_cast<const short8*>(&sXb[tr * 72 + 32 + kg * 8]);
    const ushort* kvbn = kvb + (size_t)bn * Cc * KVP;
    // phase A: 71 c-frags over 4 waves; B-frags straight from global (L2)
    for (int nf = wave; nf < 71; nf += 4) {
        int c = nf * 16 + tr;
        int ce = c < Cc ? c : Cc - 1;
        short8 b0 = *reinterpret_cast<const short8*>(&kvbn[(size_t)ce * KVP + kg * 8]);
        short8 b1 = *reinterpret_cast<const short8*>(&kvbn[(size_t)ce * KVP + 32 + kg * 8]);
        f32x4 a = (f32x4){0.f, 0.f, 0.f, 0.f};
        a = __builtin_amdgcn_mfma_f32_16x16x32_bf16(af0, b0, a, 0, 0, 0);
        a = __builtin_amdgcn_mfma_f32_16x16x32_bf16(af1, b1, a, 0, 0, 0);
        #pragma unroll
        for (int r = 0; r < 4; ++r) {   // C/D: col=lane&15 (=c), row=kg*4+r (=t)
            float g = 0.1f - 0.2f * __builtin_amdgcn_rcpf(__expf(2.0f * a[r]) + 1.0f);
            sG[(kg * 4 + r) * SGs + c] = g;
        }
    }
    __syncthreads();
    // phase B: thread owns 3 (t,e) pairs; 48-iter gather, no atomics
    int ea[3], ta[3], tea[3];
    float dxa[3];
    #pragma unroll
    for (int p = 0; p < 3; ++p) {
        int idx = tid + p * 256;
        ta[p] = idx / 48; ea[p] = idx % 48;
        tea[p] = ea[p] * (ea[p] - 1) / 2;
        dxa[p] = 0.f;
    }
    int td = 0;
    #pragma unroll 4
    for (int d = 0; d < 48; ++d) {
        #pragma unroll
        for (int p = 0; p < 3; ++p) {
            bool gt = d > ea[p];
            int c = gt ? (td + ea[p]) : (tea[p] + d);
            float gv = sG[ta[p] * SGs + c];
            float xv = sXf[ta[p] * 52 + d];
            float m = gt ? xv : -xv;
            if (d == ea[p]) m = 0.f;
            dxa[p] = fmaf(m, gv, dxa[p]);
        }
        td += d;
    }
    #pragma unroll
    for (int p = 0; p < 3; ++p) {
        int tg = t0 + ta[p];
        if (tg < Tc)
            out[(((size_t)b * Tc + tg) * Nc + n) * Dc + ea[p]] = sXf[ta[p] * 52 + ea[p]] + dxa[p];
    }
}

extern "C" void kernel_launch(void* const* d_in, const int* in_sizes, int n_in,
                              void* d_out, int out_size, void* d_ws, size_t ws_size,
                              hipStream_t stream) {
    (void)in_sizes; (void)n_in; (void)out_size; (void)ws_size;
    const float* x   = (const float*)d_in[0];
    const float* ctx = (const float*)d_in[1];
    const float* Wkv = (const float*)d_in[2];
    const float* bkv = (const float*)d_in[3];
    float* out   = (float*)d_out;
    ushort* kvb  = (ushort*)d_ws;   // 192*1128*64*2 = 27.7 MB

    k1_kv<<<dim3(BNc, 9), dim3(256), 0, stream>>>(ctx, Wkv, bkv, kvb);
    k2_fused<<<dim3(BNc * 8), dim3(256), 0, stream>>>(x, kvb, out);
}